// Round 1
// baseline (1104.204 us; speedup 1.0000x reference)
//
#include <hip/hip_runtime.h>
#include <stdint.h>

typedef unsigned short u16;
typedef unsigned long long u64;

#define N_ROWS 32768
#define DIM 256
#define K_CODES 8192
#define SPLITD 512   // per row: [hi(256) | lo(256)] f16

// workspace offsets (bytes)
#define A_OFF    0ull            // 32768*512*2 = 33554432
#define B_OFF    33554432ull     // 8192*512*2  = 8388608
#define CN_OFF   41943040ull     // 8192*4
#define GMIN_OFF 41975808ull     // 32768*8
#define HIST_OFF 42237952ull     // 8192*4
#define LOSS_OFF 42270720ull     // 4 (adjacent to hist for single memset)

// output offsets (float elements)
#define OUT_Q 0
#define OUT_T 8388608
#define OUT_S 8421376

#define BM 128
#define BN 128
#define BK 64
#define JSPLIT 2

typedef _Float16 half8 __attribute__((ext_vector_type(8)));
typedef float floatx4 __attribute__((ext_vector_type(4)));

__device__ __forceinline__ void gload_lds16(const void* g, void* l) {
    __builtin_amdgcn_global_load_lds(
        (const __attribute__((address_space(1))) void*)g,
        (__attribute__((address_space(3))) void*)l,
        16, 0, 0);
}

// fp32 -> (hi, lo) f16 split for inputs and codebook. 8 elements/thread.
__global__ void prep_split(const float* __restrict__ inp, const float* __restrict__ cb,
                           u16* __restrict__ A, u16* __restrict__ B) {
    int g = blockIdx.x * 256 + threadIdx.x;       // 40960 rows * 32 threads
    int row = g >> 5;
    int kc = (g & 31) << 3;
    const float* src;
    u16* dst;
    if (row < N_ROWS) { src = inp + (size_t)row * DIM + kc; dst = A + (size_t)row * SPLITD; }
    else              { src = cb + (size_t)(row - N_ROWS) * DIM + kc; dst = B + (size_t)(row - N_ROWS) * SPLITD; }
    float4 x0 = *(const float4*)(src);
    float4 x1 = *(const float4*)(src + 4);
    float xs[8] = {x0.x, x0.y, x0.z, x0.w, x1.x, x1.y, x1.z, x1.w};
    half8 hv, lv;
#pragma unroll
    for (int i = 0; i < 8; ++i) {
        _Float16 h = (_Float16)xs[i];
        hv[i] = h;
        lv[i] = (_Float16)(xs[i] - (float)h);
    }
    *(half8*)(dst + kc) = hv;
    *(half8*)(dst + DIM + kc) = lv;
}

// ||c_j||^2 per codebook row (one wave per row)
__global__ void cn_kernel(const float* __restrict__ cb, float* __restrict__ cn) {
    int w = threadIdx.x >> 6, lane = threadIdx.x & 63;
    int row = blockIdx.x * 4 + w;
    float4 v = ((const float4*)(cb + (size_t)row * DIM))[lane];
    float s = v.x * v.x + v.y * v.y + v.z * v.z + v.w * v.w;
#pragma unroll
    for (int m = 32; m; m >>= 1) s += __shfl_xor(s, m, 64);
    if (lane == 0) cn[row] = s;
}

// main: split-f16 MFMA GEMM (effective K=768) + running argmin
__launch_bounds__(256, 2)
__global__ void vq_main(const u16* __restrict__ A, const u16* __restrict__ B,
                        const float* __restrict__ cn, u64* __restrict__ gmin) {
    __shared__ __align__(16) _Float16 lsA[BM * BK];
    __shared__ __align__(16) _Float16 lsB[BN * BK];
    __shared__ u64 rowmin[BM];

    const int tid = threadIdx.x;
    const int lane = tid & 63;
    const int w = tid >> 6;
    const int wm = w >> 1, wn = w & 1;
    const int l15 = lane & 15;
    const int quad = lane >> 4;
    const int rowBase = blockIdx.x * BM;
    const int jBase = blockIdx.y * (K_CODES / JSPLIT);

    if (tid < BM) rowmin[tid] = ~0ull;

    u64 minpack[16];
#pragma unroll
    for (int i = 0; i < 16; ++i) minpack[i] = ~0ull;

    const int segA[3] = {0, 0, 256};   // hi, hi, lo
    const int segB[3] = {0, 256, 0};   // hi, lo, hi

    for (int jc = 0; jc < (K_CODES / JSPLIT) / BN; ++jc) {
        const int colBase = jBase + jc * BN;
        floatx4 acc[4][4];
#pragma unroll
        for (int mi = 0; mi < 4; ++mi)
#pragma unroll
            for (int ni = 0; ni < 4; ++ni)
                acc[mi][ni] = (floatx4){0.f, 0.f, 0.f, 0.f};

#pragma unroll 1
        for (int seg = 0; seg < 3; ++seg) {
            const int aoff = segA[seg], boff = segB[seg];
#pragma unroll 1
            for (int kk = 0; kk < 256; kk += BK) {
#pragma unroll
                for (int it = 0; it < 4; ++it) {
                    int ch = it * 256 + tid;          // 1024 16B chunks per tile
                    int r = ch >> 3, k16 = ch & 7;
                    gload_lds16(A + (size_t)(rowBase + r) * SPLITD + aoff + kk + k16 * 8,
                                (char*)lsA + ch * 16);
                    gload_lds16(B + (size_t)(colBase + r) * SPLITD + boff + kk + k16 * 8,
                                (char*)lsB + ch * 16);
                }
                __syncthreads();
#pragma unroll
                for (int s = 0; s < 2; ++s) {
                    const int ko = s * 32 + quad * 8;
                    half8 af[4], bf[4];
#pragma unroll
                    for (int mi = 0; mi < 4; ++mi)
                        af[mi] = *(const half8*)(lsA + (wm * 64 + mi * 16 + l15) * BK + ko);
#pragma unroll
                    for (int ni = 0; ni < 4; ++ni)
                        bf[ni] = *(const half8*)(lsB + (wn * 64 + ni * 16 + l15) * BK + ko);
#pragma unroll
                    for (int mi = 0; mi < 4; ++mi)
#pragma unroll
                        for (int ni = 0; ni < 4; ++ni)
                            acc[mi][ni] = __builtin_amdgcn_mfma_f32_16x16x32_f16(
                                af[mi], bf[ni], acc[mi][ni], 0, 0, 0);
                }
                __syncthreads();
            }
        }

        // argmin update: C/D layout col=lane&15, row=quad*4+reg
#pragma unroll
        for (int ni = 0; ni < 4; ++ni) {
            int j = colBase + wn * 64 + ni * 16 + l15;
            float cnj = cn[j];
#pragma unroll
            for (int mi = 0; mi < 4; ++mi) {
#pragma unroll
                for (int r = 0; r < 4; ++r) {
                    float val = cnj - 2.0f * acc[mi][ni][r];
                    unsigned u = __float_as_uint(val);
                    u = (u & 0x80000000u) ? ~u : (u | 0x80000000u);  // order-preserving
                    u64 pk = ((u64)u << 32) | (unsigned)j;
                    int tr = mi * 4 + r;
                    if (pk < minpack[tr]) minpack[tr] = pk;
                }
            }
        }
    }

    // reduce across the 16 lanes (bits 0..3) that share each row
#pragma unroll
    for (int m = 1; m <= 8; m <<= 1)
#pragma unroll
        for (int tr = 0; tr < 16; ++tr) {
            u64 o = __shfl_xor(minpack[tr], m, 64);
            if (o < minpack[tr]) minpack[tr] = o;
        }

    if (l15 == 0) {
#pragma unroll
        for (int tr = 0; tr < 16; ++tr) {
            int mi = tr >> 2, r = tr & 3;
            int rl = wm * 64 + mi * 16 + quad * 4 + r;
            atomicMin(&rowmin[rl], minpack[tr]);
        }
    }
    __syncthreads();
    if (tid < BM) atomicMin(&gmin[rowBase + tid], rowmin[tid]);
}

// gather codebook rows, write quantized + tokens, accumulate loss + histogram
__global__ void vq_gather(const float* __restrict__ inp, const float* __restrict__ cb,
                          const u64* __restrict__ gmin, float* __restrict__ out,
                          float* __restrict__ lossacc, unsigned int* __restrict__ hist) {
    int w = threadIdx.x >> 6, lane = threadIdx.x & 63;
    int i = blockIdx.x * 4 + w;
    unsigned idx = (unsigned)(gmin[i] & 0xffffffffull);
    float4 c = ((const float4*)(cb + (size_t)idx * DIM))[lane];
    float4 x = ((const float4*)(inp + (size_t)i * DIM))[lane];
    ((float4*)(out + OUT_Q))[(size_t)i * 64 + lane] = c;
    float dx = c.x - x.x, dy = c.y - x.y, dz = c.z - x.z, dw = c.w - x.w;
    float s = dx * dx + dy * dy + dz * dz + dw * dw;
#pragma unroll
    for (int m = 32; m; m >>= 1) s += __shfl_xor(s, m, 64);
    if (lane == 0) {
        out[OUT_T + i] = (float)idx;
        atomicAdd(lossacc, s);
        atomicAdd(&hist[idx], 1u);
    }
}

__global__ void vq_finalize(const unsigned int* __restrict__ hist,
                            const float* __restrict__ lossacc, float* __restrict__ out) {
    __shared__ float red[256];
    int tid = threadIdx.x;
    float s = 0.f;
    for (int k = tid; k < K_CODES; k += 256) {
        float p = (float)hist[k] * (1.0f / (float)N_ROWS);
        s += p * logf(p + 1e-10f);
    }
    red[tid] = s;
    __syncthreads();
    for (int st = 128; st; st >>= 1) {
        if (tid < st) red[tid] += red[tid + st];
        __syncthreads();
    }
    if (tid == 0) {
        float perp = expf(-red[0]);
        float e = lossacc[0] / 8388608.0f;   // mean((q - x)^2)
        out[OUT_S + 0] = 1.25f * e;          // vq_loss
        out[OUT_S + 1] = 0.25f * e;          // commitment_loss
        out[OUT_S + 2] = e;                  // codebook_loss
        out[OUT_S + 3] = perp;               // perplexity
    }
}

extern "C" void kernel_launch(void* const* d_in, const int* in_sizes, int n_in,
                              void* d_out, int out_size, void* d_ws, size_t ws_size,
                              hipStream_t stream) {
    const float* inp = (const float*)d_in[0];
    const float* cb = (const float*)d_in[1];
    float* out = (float*)d_out;
    char* ws = (char*)d_ws;
    u16* A = (u16*)(ws + A_OFF);
    u16* B = (u16*)(ws + B_OFF);
    float* cn = (float*)(ws + CN_OFF);
    u64* gmin = (u64*)(ws + GMIN_OFF);
    unsigned int* hist = (unsigned int*)(ws + HIST_OFF);
    float* lossacc = (float*)(ws + LOSS_OFF);

    hipMemsetAsync(gmin, 0xFF, N_ROWS * 8, stream);
    hipMemsetAsync(hist, 0, K_CODES * 4 + 256, stream);   // hist + lossacc

    prep_split<<<5120, 256, 0, stream>>>(inp, cb, A, B);
    cn_kernel<<<K_CODES / 4, 256, 0, stream>>>(cb, cn);
    vq_main<<<dim3(N_ROWS / BM, JSPLIT), 256, 0, stream>>>(A, B, cn, gmin);
    vq_gather<<<N_ROWS / 4, 256, 0, stream>>>(inp, cb, gmin, out, lossacc, hist);
    vq_finalize<<<1, 256, 0, stream>>>(hist, lossacc, out);
}

// Round 2
// 1082.771 us; speedup vs baseline: 1.0198x; 1.0198x over previous
//
#include <hip/hip_runtime.h>
#include <stdint.h>

typedef unsigned short u16;
typedef unsigned long long u64;

#define N_ROWS 32768
#define DIM 256
#define K_CODES 8192
#define SPLITD 512   // per row: [hi(256) | lo(256)] f16

// workspace offsets (bytes)
#define A_OFF    0ull            // 32768*512*2 = 33554432
#define B_OFF    33554432ull     // 8192*512*2  = 8388608
#define CN_OFF   41943040ull     // 8192*4
#define GMIN_OFF 41975808ull     // 32768*8
#define HIST_OFF 42237952ull     // 8192*4
#define LOSS_OFF 42270720ull     // 4 (adjacent to hist for single memset)

// output offsets (float elements)
#define OUT_Q 0
#define OUT_T 8388608
#define OUT_S 8421376

#define BM 128
#define BN 128
#define BK 64
#define JSPLIT 4

typedef _Float16 half8 __attribute__((ext_vector_type(8)));
typedef float floatx4 __attribute__((ext_vector_type(4)));

__device__ __forceinline__ void gload_lds16(const void* g, void* l) {
    __builtin_amdgcn_global_load_lds(
        (const __attribute__((address_space(1))) void*)g,
        (__attribute__((address_space(3))) void*)l,
        16, 0, 0);
}

// fp32 -> (hi, lo) f16 split for inputs and codebook. 8 elements/thread.
__global__ void prep_split(const float* __restrict__ inp, const float* __restrict__ cb,
                           u16* __restrict__ A, u16* __restrict__ B) {
    int g = blockIdx.x * 256 + threadIdx.x;       // 40960 rows * 32 threads
    int row = g >> 5;
    int kc = (g & 31) << 3;
    const float* src;
    u16* dst;
    if (row < N_ROWS) { src = inp + (size_t)row * DIM + kc; dst = A + (size_t)row * SPLITD; }
    else              { src = cb + (size_t)(row - N_ROWS) * DIM + kc; dst = B + (size_t)(row - N_ROWS) * SPLITD; }
    float4 x0 = *(const float4*)(src);
    float4 x1 = *(const float4*)(src + 4);
    float xs[8] = {x0.x, x0.y, x0.z, x0.w, x1.x, x1.y, x1.z, x1.w};
    half8 hv, lv;
#pragma unroll
    for (int i = 0; i < 8; ++i) {
        _Float16 h = (_Float16)xs[i];
        hv[i] = h;
        lv[i] = (_Float16)(xs[i] - (float)h);
    }
    *(half8*)(dst + kc) = hv;
    *(half8*)(dst + DIM + kc) = lv;
}

// ||c_j||^2 per codebook row (one wave per row)
__global__ void cn_kernel(const float* __restrict__ cb, float* __restrict__ cn) {
    int w = threadIdx.x >> 6, lane = threadIdx.x & 63;
    int row = blockIdx.x * 4 + w;
    float4 v = ((const float4*)(cb + (size_t)row * DIM))[lane];
    float s = v.x * v.x + v.y * v.y + v.z * v.z + v.w * v.w;
#pragma unroll
    for (int m = 32; m; m >>= 1) s += __shfl_xor(s, m, 64);
    if (lane == 0) cn[row] = s;
}

// main: split-f16 MFMA GEMM (effective K=768) + running argmin
// LDS layout XOR-swizzled: slot (r, k16) holds data chunk (k16 ^ (r&7)).
__launch_bounds__(256, 4)
__global__ void vq_main(const u16* __restrict__ A, const u16* __restrict__ B,
                        const float* __restrict__ cn, u64* __restrict__ gmin) {
    __shared__ __align__(16) _Float16 lsA[BM * BK];
    __shared__ __align__(16) _Float16 lsB[BN * BK];
    __shared__ u64 rowmin[BM];

    const int tid = threadIdx.x;
    const int lane = tid & 63;
    const int w = tid >> 6;
    const int wm = w >> 1, wn = w & 1;
    const int l15 = lane & 15;
    const int quad = lane >> 4;
    const int xm = l15 & 7;                 // XOR swizzle key (row&7 of fragment rows)
    const int rowBase = blockIdx.x * BM;
    const int jBase = blockIdx.y * (K_CODES / JSPLIT);

    if (tid < BM) rowmin[tid] = ~0ull;

    u64 minpack[16];
#pragma unroll
    for (int i = 0; i < 16; ++i) minpack[i] = ~0ull;

    const int segA[3] = {0, 0, 256};   // hi, hi, lo
    const int segB[3] = {0, 256, 0};   // hi, lo, hi

    // staging indices (constant per thread)
    const int str = tid >> 3;           // staging row 0..31 (within 256-chunk batch)
    const int sk16 = tid & 7;           // staging chunk slot 0..7

    for (int jc = 0; jc < (K_CODES / JSPLIT) / BN; ++jc) {
        const int colBase = jBase + jc * BN;
        floatx4 acc[4][4];
#pragma unroll
        for (int mi = 0; mi < 4; ++mi)
#pragma unroll
            for (int ni = 0; ni < 4; ++ni)
                acc[mi][ni] = (floatx4){0.f, 0.f, 0.f, 0.f};

#pragma unroll 1
        for (int seg = 0; seg < 3; ++seg) {
            const int aoff = segA[seg], boff = segB[seg];
#pragma unroll 1
            for (int kk = 0; kk < 256; kk += BK) {
#pragma unroll
                for (int it = 0; it < 4; ++it) {
                    int r = it * 32 + str;               // tile row 0..127
                    int cdat = sk16 ^ (r & 7);           // data chunk for this LDS slot
                    int ch = (it * 256 + tid);           // LDS slot index (lane-contiguous)
                    gload_lds16(A + (size_t)(rowBase + r) * SPLITD + aoff + kk + cdat * 8,
                                (char*)lsA + ch * 16);
                    gload_lds16(B + (size_t)(colBase + r) * SPLITD + boff + kk + cdat * 8,
                                (char*)lsB + ch * 16);
                }
                __syncthreads();
#pragma unroll
                for (int s = 0; s < 2; ++s) {
                    const int koff = ((s * 4 + quad) ^ xm) * 8;   // swizzled chunk offset (halves)
                    half8 af[4], bf[4];
#pragma unroll
                    for (int mi = 0; mi < 4; ++mi)
                        af[mi] = *(const half8*)(lsA + (wm * 64 + mi * 16 + l15) * BK + koff);
#pragma unroll
                    for (int ni = 0; ni < 4; ++ni)
                        bf[ni] = *(const half8*)(lsB + (wn * 64 + ni * 16 + l15) * BK + koff);
#pragma unroll
                    for (int mi = 0; mi < 4; ++mi)
#pragma unroll
                        for (int ni = 0; ni < 4; ++ni)
                            acc[mi][ni] = __builtin_amdgcn_mfma_f32_16x16x32_f16(
                                af[mi], bf[ni], acc[mi][ni], 0, 0, 0);
                }
                __syncthreads();
            }
        }

        // argmin update: C/D layout col=lane&15, row=quad*4+reg
#pragma unroll
        for (int ni = 0; ni < 4; ++ni) {
            int j = colBase + wn * 64 + ni * 16 + l15;
            float cnj = cn[j];
#pragma unroll
            for (int mi = 0; mi < 4; ++mi) {
#pragma unroll
                for (int r = 0; r < 4; ++r) {
                    float val = cnj - 2.0f * acc[mi][ni][r];
                    unsigned u = __float_as_uint(val);
                    u = (u & 0x80000000u) ? ~u : (u | 0x80000000u);  // order-preserving
                    u64 pk = ((u64)u << 32) | (unsigned)j;
                    int tr = mi * 4 + r;
                    if (pk < minpack[tr]) minpack[tr] = pk;
                }
            }
        }
    }

    // reduce across the 16 lanes (bits 0..3) that share each row
#pragma unroll
    for (int m = 1; m <= 8; m <<= 1)
#pragma unroll
        for (int tr = 0; tr < 16; ++tr) {
            u64 o = __shfl_xor(minpack[tr], m, 64);
            if (o < minpack[tr]) minpack[tr] = o;
        }

    if (l15 == 0) {
#pragma unroll
        for (int tr = 0; tr < 16; ++tr) {
            int mi = tr >> 2, r = tr & 3;
            int rl = wm * 64 + mi * 16 + quad * 4 + r;
            atomicMin(&rowmin[rl], minpack[tr]);
        }
    }
    __syncthreads();
    if (tid < BM) atomicMin(&gmin[rowBase + tid], rowmin[tid]);
}

// gather codebook rows, write quantized + tokens, accumulate loss + histogram
__global__ void vq_gather(const float* __restrict__ inp, const float* __restrict__ cb,
                          const u64* __restrict__ gmin, float* __restrict__ out,
                          float* __restrict__ lossacc, unsigned int* __restrict__ hist) {
    int w = threadIdx.x >> 6, lane = threadIdx.x & 63;
    int i = blockIdx.x * 4 + w;
    unsigned idx = (unsigned)(gmin[i] & 0xffffffffull);
    float4 c = ((const float4*)(cb + (size_t)idx * DIM))[lane];
    float4 x = ((const float4*)(inp + (size_t)i * DIM))[lane];
    ((float4*)(out + OUT_Q))[(size_t)i * 64 + lane] = c;
    float dx = c.x - x.x, dy = c.y - x.y, dz = c.z - x.z, dw = c.w - x.w;
    float s = dx * dx + dy * dy + dz * dz + dw * dw;
#pragma unroll
    for (int m = 32; m; m >>= 1) s += __shfl_xor(s, m, 64);
    if (lane == 0) {
        out[OUT_T + i] = (float)idx;
        atomicAdd(lossacc, s);
        atomicAdd(&hist[idx], 1u);
    }
}

__global__ void vq_finalize(const unsigned int* __restrict__ hist,
                            const float* __restrict__ lossacc, float* __restrict__ out) {
    __shared__ float red[256];
    int tid = threadIdx.x;
    float s = 0.f;
    for (int k = tid; k < K_CODES; k += 256) {
        float p = (float)hist[k] * (1.0f / (float)N_ROWS);
        s += p * logf(p + 1e-10f);
    }
    red[tid] = s;
    __syncthreads();
    for (int st = 128; st; st >>= 1) {
        if (tid < st) red[tid] += red[tid + st];
        __syncthreads();
    }
    if (tid == 0) {
        float perp = expf(-red[0]);
        float e = lossacc[0] / 8388608.0f;   // mean((q - x)^2)
        out[OUT_S + 0] = 1.25f * e;          // vq_loss
        out[OUT_S + 1] = 0.25f * e;          // commitment_loss
        out[OUT_S + 2] = e;                  // codebook_loss
        out[OUT_S + 3] = perp;               // perplexity
    }
}

extern "C" void kernel_launch(void* const* d_in, const int* in_sizes, int n_in,
                              void* d_out, int out_size, void* d_ws, size_t ws_size,
                              hipStream_t stream) {
    const float* inp = (const float*)d_in[0];
    const float* cb = (const float*)d_in[1];
    float* out = (float*)d_out;
    char* ws = (char*)d_ws;
    u16* A = (u16*)(ws + A_OFF);
    u16* B = (u16*)(ws + B_OFF);
    float* cn = (float*)(ws + CN_OFF);
    u64* gmin = (u64*)(ws + GMIN_OFF);
    unsigned int* hist = (unsigned int*)(ws + HIST_OFF);
    float* lossacc = (float*)(ws + LOSS_OFF);

    hipMemsetAsync(gmin, 0xFF, N_ROWS * 8, stream);
    hipMemsetAsync(hist, 0, K_CODES * 4 + 256, stream);   // hist + lossacc

    prep_split<<<5120, 256, 0, stream>>>(inp, cb, A, B);
    cn_kernel<<<K_CODES / 4, 256, 0, stream>>>(cb, cn);
    vq_main<<<dim3(N_ROWS / BM, JSPLIT), 256, 0, stream>>>(A, B, cn, gmin);
    vq_gather<<<N_ROWS / 4, 256, 0, stream>>>(inp, cb, gmin, out, lossacc, hist);
    vq_finalize<<<1, 256, 0, stream>>>(hist, lossacc, out);
}